// Round 1
// baseline (2397.519 us; speedup 1.0000x reference)
//
#include <hip/hip_runtime.h>
#include <math.h>

#define NN 50000
#define IND 128
#define NH 4
#define HD 32
#define NE 800000
#define NSLOPE 0.2f

// monotone float<->uint encoding so unsigned atomicMax == float max (handles negatives, -inf)
__device__ __forceinline__ unsigned enc_f(float f) {
    unsigned b = __float_as_uint(f);
    return (b & 0x80000000u) ? ~b : (b | 0x80000000u);
}
__device__ __forceinline__ float dec_f(unsigned u) {
    return __uint_as_float((u & 0x80000000u) ? (u ^ 0x80000000u) : ~u);
}
#define ENC_NEG_INF 0x007FFFFFu  // enc_f(-inf)

// h = x @ W_t  (+ fused e_src/e_dst head reductions)
// block: 128 threads (one output column each), W_t staged in LDS (64KB)
__global__ __launch_bounds__(128) void gemm_esrc_kernel(
    const float* __restrict__ x, const float* __restrict__ Wt,
    const float* __restrict__ asrc, const float* __restrict__ adst,
    float* __restrict__ h, float* __restrict__ es, float* __restrict__ ed,
    int npb)
{
    __shared__ float Ws[IND * IND];
    __shared__ float xs[IND];
    const int tid = threadIdx.x;          // output column c = head*32 + k
    for (int i = tid; i < IND * IND; i += 128) Ws[i] = Wt[i];
    const float ac = asrc[tid];
    const float bc = adst[tid];
    __syncthreads();
    int n0 = blockIdx.x * npb;
    int n1 = n0 + npb; if (n1 > NN) n1 = NN;
    for (int n = n0; n < n1; n++) {
        xs[tid] = x[n * IND + tid];
        __syncthreads();
        float acc = 0.f;
        #pragma unroll
        for (int d = 0; d < IND; d++) acc = fmaf(xs[d], Ws[d * IND + tid], acc);
        h[n * IND + tid] = acc;
        // per-head (32-lane group) reductions for e_src / e_dst
        float vs = acc * ac, vd = acc * bc;
        #pragma unroll
        for (int m = 16; m >= 1; m >>= 1) {
            vs += __shfl_xor(vs, m, 32);
            vd += __shfl_xor(vd, m, 32);
        }
        if ((tid & 31) == 0) {
            es[n * NH + (tid >> 5)] = vs;
            ed[n * NH + (tid >> 5)] = vd;
        }
        __syncthreads();
    }
}

__global__ __launch_bounds__(256) void init_kernel(
    unsigned* __restrict__ m_enc, float* __restrict__ denom, float* __restrict__ agg)
{
    int i = blockIdx.x * 256 + threadIdx.x;
    if (i < NN * NH) { m_enc[i] = ENC_NEG_INF; denom[i] = 0.f; }
    if (i < NN * IND) agg[i] = 0.f;
}

// per edge: score s = leaky_relu(e_src[src]+e_dst[dst]); atomicMax into m_enc[dst]; stash scores
__global__ __launch_bounds__(256) void edge_max_kernel(
    const int* __restrict__ src_idx, const int* __restrict__ dst_idx,
    const float* __restrict__ es, const float* __restrict__ ed,
    float* __restrict__ sc, unsigned* __restrict__ m_enc)
{
    int e = blockIdx.x * 256 + threadIdx.x;
    if (e >= NE) return;
    int s = src_idx[e], d = dst_idx[e];
    const float4 s4 = *reinterpret_cast<const float4*>(es + (size_t)s * NH);
    const float4 d4 = *reinterpret_cast<const float4*>(ed + (size_t)d * NH);
    float v[4] = { s4.x + d4.x, s4.y + d4.y, s4.z + d4.z, s4.w + d4.w };
    #pragma unroll
    for (int hh = 0; hh < 4; hh++) {
        float tv = v[hh];
        tv = tv > 0.f ? tv : NSLOPE * tv;
        v[hh] = tv;
        atomicMax(&m_enc[(size_t)d * NH + hh], enc_f(tv));
    }
    *reinterpret_cast<float4*>(sc + (size_t)e * NH) = make_float4(v[0], v[1], v[2], v[3]);
}

// per edge: w = exp(s - m[dst]); denom[dst] += w; store w over scores
__global__ __launch_bounds__(256) void edge_w_kernel(
    const int* __restrict__ dst_idx,
    float* __restrict__ sc, const unsigned* __restrict__ m_enc,
    float* __restrict__ denom)
{
    int e = blockIdx.x * 256 + threadIdx.x;
    if (e >= NE) return;
    int d = dst_idx[e];
    float4 v4 = *reinterpret_cast<float4*>(sc + (size_t)e * NH);
    const uint4 m4 = *reinterpret_cast<const uint4*>(m_enc + (size_t)d * NH);
    float w0 = expf(v4.x - dec_f(m4.x));
    float w1 = expf(v4.y - dec_f(m4.y));
    float w2 = expf(v4.z - dec_f(m4.z));
    float w3 = expf(v4.w - dec_f(m4.w));
    unsafeAtomicAdd(&denom[(size_t)d * NH + 0], w0);
    unsafeAtomicAdd(&denom[(size_t)d * NH + 1], w1);
    unsafeAtomicAdd(&denom[(size_t)d * NH + 2], w2);
    unsafeAtomicAdd(&denom[(size_t)d * NH + 3], w3);
    *reinterpret_cast<float4*>(sc + (size_t)e * NH) = make_float4(w0, w1, w2, w3);
}

// per (edge, dim): agg[dst, dim] += h[src, dim] * w[edge, head(dim)]
// 128 consecutive threads share one edge -> coalesced gather + coalesced atomics
__global__ __launch_bounds__(256) void edge_agg_kernel(
    const int* __restrict__ src_idx, const int* __restrict__ dst_idx,
    const float* __restrict__ h, const float* __restrict__ sc,
    float* __restrict__ agg)
{
    long long gid = (long long)blockIdx.x * 256 + threadIdx.x;
    int e = (int)(gid >> 7);
    if (e >= NE) return;
    int dd = (int)(gid & 127);
    int s = src_idx[e], d = dst_idx[e];
    float wv = sc[(size_t)e * NH + (dd >> 5)];
    unsafeAtomicAdd(&agg[(size_t)d * IND + dd], h[(size_t)s * IND + dd] * wv);
}

// out = elu(agg / (denom + 1e-9)); write gat and gcn copies
__global__ __launch_bounds__(256) void final_kernel(
    const float* __restrict__ agg, const float* __restrict__ denom,
    float* __restrict__ outa, float* __restrict__ outb)
{
    int i = blockIdx.x * 256 + threadIdx.x;
    if (i >= NN * IND) return;
    int n = i >> 7, dd = i & 127;
    float v = agg[i] / (denom[(size_t)n * NH + (dd >> 5)] + 1e-9f);
    float r = v > 0.f ? v : expm1f(v);
    outa[i] = r;
    outb[i] = r;
}

extern "C" void kernel_launch(void* const* d_in, const int* in_sizes, int n_in,
                              void* d_out, int out_size, void* d_ws, size_t ws_size,
                              hipStream_t stream)
{
    const float* x     = (const float*)d_in[0];
    const int*   edges = (const int*)d_in[1];
    const float* W     = (const float*)d_in[2];
    const float* asrc  = (const float*)d_in[3];
    const float* adst  = (const float*)d_in[4];
    float* out = (float*)d_out;

    char* p = (char*)d_ws;
    float*    h     = (float*)p;    p += (size_t)NN * IND * 4;
    float*    es    = (float*)p;    p += (size_t)NN * NH * 4;
    float*    ed    = (float*)p;    p += (size_t)NN * NH * 4;
    unsigned* m_enc = (unsigned*)p; p += (size_t)NN * NH * 4;
    float*    denom = (float*)p;    p += (size_t)NN * NH * 4;
    float*    agg   = (float*)p;    p += (size_t)NN * IND * 4;
    float*    sc    = (float*)p;    p += (size_t)NE * NH * 4;

    const int npb = (NN + 511) / 512;

    for (int t = 0; t < 3; t++) {
        const int* src_idx = edges + (size_t)t * 2 * NE;
        const int* dst_idx = src_idx + NE;
        const float* Wt = W + (size_t)t * IND * IND;
        const float* at = asrc + (size_t)t * NH * HD;
        const float* bt = adst + (size_t)t * NH * HD;

        gemm_esrc_kernel<<<512, 128, 0, stream>>>(x, Wt, at, bt, h, es, ed, npb);
        init_kernel<<<(NN * IND + 255) / 256, 256, 0, stream>>>(m_enc, denom, agg);
        edge_max_kernel<<<(NE + 255) / 256, 256, 0, stream>>>(src_idx, dst_idx, es, ed, sc, m_enc);
        edge_w_kernel<<<(NE + 255) / 256, 256, 0, stream>>>(dst_idx, sc, m_enc, denom);
        edge_agg_kernel<<<(NE * 128) / 256, 256, 0, stream>>>(src_idx, dst_idx, h, sc, agg);
        final_kernel<<<(NN * IND + 255) / 256, 256, 0, stream>>>(
            agg, denom, out + (size_t)t * NN * IND, out + (size_t)(3 + t) * NN * IND);
    }
}

// Round 2
// 946.346 us; speedup vs baseline: 2.5334x; 2.5334x over previous
//
#include <hip/hip_runtime.h>
#include <math.h>

#define NN 50000
#define IND 128
#define NH 4
#define HD 32
#define NE 800000
#define NSLOPE 0.2f

// ---------------- GEMM + fused e_src/e_dst ----------------
// h = x @ W_t ; es/ed = per-head reductions of h*a_src / h*a_dst
__global__ __launch_bounds__(128) void gemm_esrc_kernel(
    const float* __restrict__ x, const float* __restrict__ Wt,
    const float* __restrict__ asrc, const float* __restrict__ adst,
    float* __restrict__ h, float* __restrict__ es, float* __restrict__ ed,
    int npb)
{
    __shared__ float Ws[IND * IND];
    __shared__ float xs[IND];
    const int tid = threadIdx.x;          // output column c = head*32 + k
    for (int i = tid; i < IND * IND; i += 128) Ws[i] = Wt[i];
    const float ac = asrc[tid];
    const float bc = adst[tid];
    __syncthreads();
    int n0 = blockIdx.x * npb;
    int n1 = n0 + npb; if (n1 > NN) n1 = NN;
    for (int n = n0; n < n1; n++) {
        xs[tid] = x[n * IND + tid];
        __syncthreads();
        float acc = 0.f;
        #pragma unroll
        for (int d = 0; d < IND; d++) acc = fmaf(xs[d], Ws[d * IND + tid], acc);
        h[n * IND + tid] = acc;
        float vs = acc * ac, vd = acc * bc;
        #pragma unroll
        for (int m = 16; m >= 1; m >>= 1) {
            vs += __shfl_xor(vs, m, 32);
            vd += __shfl_xor(vd, m, 32);
        }
        if ((tid & 31) == 0) {
            es[n * NH + (tid >> 5)] = vs;
            ed[n * NH + (tid >> 5)] = vd;
        }
        __syncthreads();
    }
}

// ---------------- CSR build: zero -> hist -> scan(3) -> scatter ----------------
__global__ __launch_bounds__(256) void zero_kernel(int* __restrict__ counts)
{
    int i = blockIdx.x * 256 + threadIdx.x;
    if (i < NN) counts[i] = 0;
}

__global__ __launch_bounds__(256) void hist_kernel(
    const int* __restrict__ dst_idx, int* __restrict__ counts)
{
    int e = blockIdx.x * 256 + threadIdx.x;
    if (e < NE) atomicAdd(&counts[dst_idx[e]], 1);
}

// level-1: per-block (512) exclusive scan, emit block sums
__global__ __launch_bounds__(512) void scan1_kernel(
    const int* __restrict__ counts, int* __restrict__ offs, int* __restrict__ bsums)
{
    __shared__ int sd[512];
    int tid = threadIdx.x;
    int i = blockIdx.x * 512 + tid;
    int c = (i < NN) ? counts[i] : 0;
    sd[tid] = c;
    __syncthreads();
    for (int off = 1; off < 512; off <<= 1) {
        int v = (tid >= off) ? sd[tid - off] : 0;
        __syncthreads();
        sd[tid] += v;
        __syncthreads();
    }
    if (i < NN) offs[i] = sd[tid] - c;       // local exclusive
    if (tid == 511) bsums[blockIdx.x] = sd[511];
}

// level-2: serial scan of 98 block sums (trivial)
__global__ void scan2_kernel(int* __restrict__ bsums, int* __restrict__ boffs, int nb)
{
    if (threadIdx.x == 0 && blockIdx.x == 0) {
        int run = 0;
        for (int i = 0; i < nb; i++) { boffs[i] = run; run += bsums[i]; }
    }
}

// level-3: add block offsets, copy to cursor, set sentinel
__global__ __launch_bounds__(256) void scan3_kernel(
    int* __restrict__ offs, const int* __restrict__ boffs, int* __restrict__ cursor)
{
    int i = blockIdx.x * 256 + threadIdx.x;
    if (i < NN) {
        int o = offs[i] + boffs[i >> 9];
        offs[i] = o;
        cursor[i] = o;
    }
    if (i == 0) offs[NN] = NE;
}

__global__ __launch_bounds__(256) void scatter_kernel(
    const int* __restrict__ src_idx, const int* __restrict__ dst_idx,
    int* __restrict__ cursor, int* __restrict__ ssrc)
{
    int e = blockIdx.x * 256 + threadIdx.x;
    if (e >= NE) return;
    int d = dst_idx[e];
    int pos = atomicAdd(&cursor[d], 1);
    ssrc[pos] = src_idx[e];
}

// ---------------- fused score+softmax+aggregate+ELU, one wave per dst ----------------
__global__ __launch_bounds__(256) void gat_fused_kernel(
    const int* __restrict__ offs, const int* __restrict__ ssrc,
    const float* __restrict__ es, const float* __restrict__ ed,
    const float* __restrict__ h,
    float* __restrict__ outa, float* __restrict__ outb)
{
    const int dst  = blockIdx.x * 4 + (threadIdx.x >> 6);
    const int lane = threadIdx.x & 63;
    if (dst >= NN) return;
    const int beg = offs[dst], end = offs[dst + 1];

    const int h0 = lane >> 5;        // head of dim d0 = lane
    const int h1 = h0 + 2;           // head of dim d1 = lane + 64
    const float edv = ed[(dst << 2) + (lane & 3)];   // phase-1 operand (head = lane&3)

    float acc0 = 0.f, acc1 = 0.f, dsum = 0.f;

    for (int base = beg; base < end; base += 16) {
        int ne = end - base; if (ne > 16) ne = 16;
        const int ei = lane >> 2;
        float wv = 0.f; int sv = 0;
        if (ei < ne) {
            sv = ssrc[base + ei];
            float s = es[(sv << 2) + (lane & 3)] + edv;
            s = s > 0.f ? s : NSLOPE * s;
            wv = __expf(s);
            dsum += wv;
        }
        for (int k = 0; k < ne; k++) {
            int   s  = __shfl(sv, k << 2, 64);
            float w0 = __shfl(wv, (k << 2) | h0, 64);
            float w1 = __shfl(wv, (k << 2) | h1, 64);
            const float* hp = h + ((size_t)s << 7);
            acc0 = fmaf(w0, hp[lane],      acc0);
            acc1 = fmaf(w1, hp[64 + lane], acc1);
        }
    }

    // reduce dsum across lanes with equal (lane&3): bits 2..5
    #pragma unroll
    for (int m = 4; m <= 32; m <<= 1) dsum += __shfl_xor(dsum, m, 64);
    float d0 = __shfl(dsum, h0, 64);
    float d1 = __shfl(dsum, h1, 64);

    float v0 = acc0 / (d0 + 1e-9f);
    float v1 = acc1 / (d1 + 1e-9f);
    float r0 = v0 > 0.f ? v0 : expm1f(v0);
    float r1 = v1 > 0.f ? v1 : expm1f(v1);

    const size_t o = (size_t)dst << 7;
    outa[o + lane]      = r0;
    outa[o + 64 + lane] = r1;
    outb[o + lane]      = r0;
    outb[o + 64 + lane] = r1;
}

extern "C" void kernel_launch(void* const* d_in, const int* in_sizes, int n_in,
                              void* d_out, int out_size, void* d_ws, size_t ws_size,
                              hipStream_t stream)
{
    const float* x     = (const float*)d_in[0];
    const int*   edges = (const int*)d_in[1];
    const float* W     = (const float*)d_in[2];
    const float* asrc  = (const float*)d_in[3];
    const float* adst  = (const float*)d_in[4];
    float* out = (float*)d_out;

    char* p = (char*)d_ws;
    float* h      = (float*)p; p += (size_t)NN * IND * 4;
    float* es     = (float*)p; p += (size_t)NN * NH * 4;
    float* ed     = (float*)p; p += (size_t)NN * NH * 4;
    int*   counts = (int*)p;   p += (size_t)NN * 4;
    int*   offs   = (int*)p;   p += (size_t)(NN + 1) * 4;
    int*   cursor = (int*)p;   p += (size_t)NN * 4;
    int*   bsums  = (int*)p;   p += 256 * 4;
    int*   boffs  = (int*)p;   p += 256 * 4;
    int*   ssrc   = (int*)p;   p += (size_t)NE * 4;

    const int npb  = (NN + 511) / 512;
    const int nsb  = (NN + 511) / 512;   // scan1 blocks (98)

    for (int t = 0; t < 3; t++) {
        const int* src_idx = edges + (size_t)t * 2 * NE;
        const int* dst_idx = src_idx + NE;
        const float* Wt = W + (size_t)t * IND * IND;
        const float* at = asrc + (size_t)t * NH * HD;
        const float* bt = adst + (size_t)t * NH * HD;

        gemm_esrc_kernel<<<512, 128, 0, stream>>>(x, Wt, at, bt, h, es, ed, npb);
        zero_kernel<<<(NN + 255) / 256, 256, 0, stream>>>(counts);
        hist_kernel<<<(NE + 255) / 256, 256, 0, stream>>>(dst_idx, counts);
        scan1_kernel<<<nsb, 512, 0, stream>>>(counts, offs, bsums);
        scan2_kernel<<<1, 64, 0, stream>>>(bsums, boffs, nsb);
        scan3_kernel<<<(NN + 255) / 256, 256, 0, stream>>>(offs, boffs, cursor);
        scatter_kernel<<<(NE + 255) / 256, 256, 0, stream>>>(src_idx, dst_idx, cursor, ssrc);
        gat_fused_kernel<<<(NN + 3) / 4, 256, 0, stream>>>(
            offs, ssrc, es, ed, h,
            out + (size_t)t * NN * IND, out + (size_t)(3 + t) * NN * IND);
    }
}

// Round 3
// 739.050 us; speedup vs baseline: 3.2441x; 1.2805x over previous
//
#include <hip/hip_runtime.h>
#include <math.h>

#define NN 50000
#define IND 128
#define NH 4
#define HD 32
#define NE 800000
#define NSLOPE 0.2f
#define NT 3

// ---------------- GEMM + fused e_src/e_dst ----------------
// One wave = 8 rows x 128 cols. W staged in LDS as float2 pairs {W[k][c], W[k][c+64]}
// (one ds_read_b64 per k per lane). x rows read wave-uniformly (scalarized loads).
// No per-row barriers.
__global__ __launch_bounds__(256) void gemm_esrc_kernel(
    const float* __restrict__ x, const float* __restrict__ Wt,
    const float* __restrict__ asrc, const float* __restrict__ adst,
    float* __restrict__ h, float* __restrict__ es, float* __restrict__ ed)
{
    __shared__ float2 ws[IND * 64];   // ws[k*64 + l] = {W[k][l], W[k][64+l]}
    const int tid = threadIdx.x;
    // stage W (64KB)
    for (int idx = tid; idx < IND * 64; idx += 256) {
        int k = idx >> 6, l = idx & 63;
        ws[idx] = make_float2(Wt[k * IND + l], Wt[k * IND + 64 + l]);
    }
    __syncthreads();

    const int wv   = __builtin_amdgcn_readfirstlane(tid >> 6);
    const int lane = tid & 63;
    const int n0   = blockIdx.x * 32 + wv * 8;
    if (n0 >= NN) return;   // only trailing waves of the last block (after barrier)

    const float aA = asrc[lane], aB = asrc[64 + lane];
    const float bA = adst[lane], bB = adst[64 + lane];

    float accA[8] = {0,0,0,0,0,0,0,0};
    float accB[8] = {0,0,0,0,0,0,0,0};

    const float4* xr0 = reinterpret_cast<const float4*>(x + (size_t)n0 * IND);

    #pragma unroll 4
    for (int kc = 0; kc < 32; kc++) {           // 4 k's per iteration
        float2 w0 = ws[(kc * 4 + 0) * 64 + lane];
        float2 w1 = ws[(kc * 4 + 1) * 64 + lane];
        float2 w2 = ws[(kc * 4 + 2) * 64 + lane];
        float2 w3 = ws[(kc * 4 + 3) * 64 + lane];
        #pragma unroll
        for (int r = 0; r < 8; r++) {
            float4 xv = xr0[r * 32 + kc];       // wave-uniform -> s_load
            accA[r] = fmaf(xv.x, w0.x, accA[r]);
            accB[r] = fmaf(xv.x, w0.y, accB[r]);
            accA[r] = fmaf(xv.y, w1.x, accA[r]);
            accB[r] = fmaf(xv.y, w1.y, accB[r]);
            accA[r] = fmaf(xv.z, w2.x, accA[r]);
            accB[r] = fmaf(xv.z, w2.y, accB[r]);
            accA[r] = fmaf(xv.w, w3.x, accA[r]);
            accB[r] = fmaf(xv.w, w3.y, accB[r]);
        }
    }

    #pragma unroll
    for (int r = 0; r < 8; r++) {
        const int n = n0 + r;
        h[(size_t)n * IND + lane]      = accA[r];
        h[(size_t)n * IND + 64 + lane] = accB[r];
        float vsA = accA[r] * aA, vdA = accA[r] * bA;
        float vsB = accB[r] * aB, vdB = accB[r] * bB;
        #pragma unroll
        for (int m = 1; m <= 16; m <<= 1) {      // reduce within 32-lane halves
            vsA += __shfl_xor(vsA, m, 64);
            vdA += __shfl_xor(vdA, m, 64);
            vsB += __shfl_xor(vsB, m, 64);
            vdB += __shfl_xor(vdB, m, 64);
        }
        if ((lane & 31) == 0) {
            int hd = lane >> 5;                  // 0 or 1
            es[n * NH + hd]     = vsA;
            es[n * NH + 2 + hd] = vsB;
            ed[n * NH + hd]     = vdA;
            ed[n * NH + 2 + hd] = vdB;
        }
    }
}

// ---------------- CSR build for ALL 3 types at once ----------------
__global__ __launch_bounds__(256) void zero3_kernel(int* __restrict__ counts)
{
    int i = blockIdx.x * 256 + threadIdx.x;
    if (i < NT * NN) counts[i] = 0;
}

__global__ __launch_bounds__(256) void hist3_kernel(
    const int* __restrict__ edges, int* __restrict__ counts)
{
    int g = blockIdx.x * 256 + threadIdx.x;
    if (g >= NT * NE) return;
    int t = g / NE, e = g - t * NE;
    int d = edges[(size_t)t * 2 * NE + NE + e];
    atomicAdd(&counts[t * NN + d], 1);
}

// level-1: per-block (512) exclusive scan over 3*NN counts, emit block sums
__global__ __launch_bounds__(512) void scan1_kernel(
    const int* __restrict__ counts, int* __restrict__ offs, int* __restrict__ bsums)
{
    __shared__ int sd[512];
    int tid = threadIdx.x;
    int i = blockIdx.x * 512 + tid;
    int c = (i < NT * NN) ? counts[i] : 0;
    sd[tid] = c;
    __syncthreads();
    for (int off = 1; off < 512; off <<= 1) {
        int v = (tid >= off) ? sd[tid - off] : 0;
        __syncthreads();
        sd[tid] += v;
        __syncthreads();
    }
    if (i < NT * NN) offs[i] = sd[tid] - c;
    if (tid == 511) bsums[blockIdx.x] = sd[511];
}

// level-2: single-block scan of block sums (nb <= 512)
__global__ __launch_bounds__(512) void scan2_kernel(
    int* __restrict__ bsums, int* __restrict__ boffs, int nb)
{
    __shared__ int sd[512];
    int tid = threadIdx.x;
    int c = (tid < nb) ? bsums[tid] : 0;
    sd[tid] = c;
    __syncthreads();
    for (int off = 1; off < 512; off <<= 1) {
        int v = (tid >= off) ? sd[tid - off] : 0;
        __syncthreads();
        sd[tid] += v;
        __syncthreads();
    }
    if (tid < nb) boffs[tid] = sd[tid] - c;
}

__global__ __launch_bounds__(256) void scan3_kernel(
    int* __restrict__ offs, const int* __restrict__ boffs, int* __restrict__ cursor)
{
    int i = blockIdx.x * 256 + threadIdx.x;
    if (i < NT * NN) {
        int o = offs[i] + boffs[i >> 9];
        offs[i] = o;
        cursor[i] = o;
    }
    if (i == 0) offs[NT * NN] = NT * NE;
}

__global__ __launch_bounds__(256) void scatter3_kernel(
    const int* __restrict__ edges, int* __restrict__ cursor, int* __restrict__ ssrc)
{
    int g = blockIdx.x * 256 + threadIdx.x;
    if (g >= NT * NE) return;
    int t = g / NE, e = g - t * NE;
    const int* base = edges + (size_t)t * 2 * NE;
    int s = base[e], d = base[NE + e];
    int pos = atomicAdd(&cursor[t * NN + d], 1);
    ssrc[pos] = s;
}

// ---------------- fused score+softmax+aggregate+ELU, one wave per dst ----------------
__global__ __launch_bounds__(256) void gat_fused_kernel(
    const int* __restrict__ offs, const int* __restrict__ ssrc,
    const float* __restrict__ es, const float* __restrict__ ed,
    const float* __restrict__ h,
    float* __restrict__ outa, float* __restrict__ outb)
{
    const int dst  = blockIdx.x * 4 + (threadIdx.x >> 6);
    const int lane = threadIdx.x & 63;
    if (dst >= NN) return;
    const int beg = offs[dst], end = offs[dst + 1];

    const int h0 = lane >> 5;        // head of dim d0 = lane
    const int h1 = h0 + 2;           // head of dim d1 = lane + 64
    const float edv = ed[(dst << 2) + (lane & 3)];

    float acc0 = 0.f, acc1 = 0.f, dsum = 0.f;

    for (int base = beg; base < end; base += 16) {
        int ne = end - base; if (ne > 16) ne = 16;
        const int ei = lane >> 2;
        float wv = 0.f; int sv = 0;
        if (ei < ne) {
            sv = ssrc[base + ei];
            float s = es[(sv << 2) + (lane & 3)] + edv;
            s = s > 0.f ? s : NSLOPE * s;
            wv = __expf(s);
            dsum += wv;
        }
        for (int k = 0; k < ne; k++) {
            int   s  = __shfl(sv, k << 2, 64);
            float w0 = __shfl(wv, (k << 2) | h0, 64);
            float w1 = __shfl(wv, (k << 2) | h1, 64);
            const float* hp = h + ((size_t)s << 7);
            acc0 = fmaf(w0, hp[lane],      acc0);
            acc1 = fmaf(w1, hp[64 + lane], acc1);
        }
    }

    #pragma unroll
    for (int m = 4; m <= 32; m <<= 1) dsum += __shfl_xor(dsum, m, 64);
    float d0 = __shfl(dsum, h0, 64);
    float d1 = __shfl(dsum, h1, 64);

    float v0 = acc0 / (d0 + 1e-9f);
    float v1 = acc1 / (d1 + 1e-9f);
    float r0 = v0 > 0.f ? v0 : expm1f(v0);
    float r1 = v1 > 0.f ? v1 : expm1f(v1);

    const size_t o = (size_t)dst << 7;
    outa[o + lane]      = r0;
    outa[o + 64 + lane] = r1;
    outb[o + lane]      = r0;
    outb[o + 64 + lane] = r1;
}

extern "C" void kernel_launch(void* const* d_in, const int* in_sizes, int n_in,
                              void* d_out, int out_size, void* d_ws, size_t ws_size,
                              hipStream_t stream)
{
    const float* x     = (const float*)d_in[0];
    const int*   edges = (const int*)d_in[1];
    const float* W     = (const float*)d_in[2];
    const float* asrc  = (const float*)d_in[3];
    const float* adst  = (const float*)d_in[4];
    float* out = (float*)d_out;

    char* p = (char*)d_ws;
    float* h      = (float*)p; p += (size_t)NN * IND * 4;
    float* es     = (float*)p; p += (size_t)NN * NH * 4;
    float* ed     = (float*)p; p += (size_t)NN * NH * 4;
    int*   counts = (int*)p;   p += (size_t)NT * NN * 4;
    int*   offs   = (int*)p;   p += ((size_t)NT * NN + 1) * 4;
    int*   cursor = (int*)p;   p += (size_t)NT * NN * 4;
    int*   bsums  = (int*)p;   p += 512 * 4;
    int*   boffs  = (int*)p;   p += 512 * 4;
    int*   ssrc   = (int*)p;   p += (size_t)NT * NE * 4;

    const int nsb = (NT * NN + 511) / 512;   // 293 scan blocks

    // CSR for all 3 types (independent of h)
    zero3_kernel<<<(NT * NN + 255) / 256, 256, 0, stream>>>(counts);
    hist3_kernel<<<(NT * NE + 255) / 256, 256, 0, stream>>>(edges, counts);
    scan1_kernel<<<nsb, 512, 0, stream>>>(counts, offs, bsums);
    scan2_kernel<<<1, 512, 0, stream>>>(bsums, boffs, nsb);
    scan3_kernel<<<(NT * NN + 255) / 256, 256, 0, stream>>>(offs, boffs, cursor);
    scatter3_kernel<<<(NT * NE + 255) / 256, 256, 0, stream>>>(edges, cursor, ssrc);

    for (int t = 0; t < NT; t++) {
        const float* Wt = W + (size_t)t * IND * IND;
        const float* at = asrc + (size_t)t * NH * HD;
        const float* bt = adst + (size_t)t * NH * HD;

        gemm_esrc_kernel<<<(NN + 31) / 32, 256, 0, stream>>>(x, Wt, at, bt, h, es, ed);
        gat_fused_kernel<<<(NN + 3) / 4, 256, 0, stream>>>(
            offs + (size_t)t * NN, ssrc, es, ed, h,
            out + (size_t)t * NN * IND, out + (size_t)(NT + t) * NN * IND);
    }
}